// Round 18
// baseline (791.581 us; speedup 1.0000x reference)
//
#include <hip/hip_runtime.h>
#include <hip/hip_cooperative_groups.h>
#include <math.h>

namespace cg = cooperative_groups;

#define NN 100000
#define NE 1600000
#define HD 32
#define NG 64
#define NC 8

#define P 256        // partitions
#define PART 391     // nodes per partition; 391*256 = 100096 >= NN
#define SCAP 7000    // staging capacity per partition (Poisson(6250), +9 sigma)
#define CH 8192      // edges per bin logical block
#define NBIN ((NE + CH - 1) / CH)     // 196
#define GEMM0_LOGICAL (NN / 8)        // 12500 (8 nodes per 256-thr logical block)
#define GATHER_LOGICAL (NN / 32)      // 3125 (32 nodes per logical block)
#define POOL_LOGICAL (NG * 16)        // 1024
#define CAPL 1024                     // LDS pairs-slice capacity (mean 512)

__device__ __forceinline__ float bf2f(unsigned short u) {
    return __uint_as_float(((unsigned int)u) << 16);
}
__device__ __forceinline__ unsigned short f2bf(float f) {
    unsigned int b = __float_as_uint(f);
    b = (b + 0x7FFFu + ((b >> 16) & 1u)) >> 16;  // RNE
    return (unsigned short)b;
}

// ---- fp8 helpers: hardware cvt if available, manual e4m3 fallback ----
#if __has_builtin(__builtin_amdgcn_cvt_pk_f32_fp8) && __has_builtin(__builtin_amdgcn_cvt_pk_fp8_f32)
#define FP8_HW 1
#else
#define FP8_HW 0
#endif

__device__ __forceinline__ float e4m3f_sw(unsigned u) {
    unsigned code = u & 0x7fu;
    unsigned e = code >> 3;
    float v;
    if (e == 0) v = (float)code * 0.001953125f;
    else v = __uint_as_float(((e + 120u) << 23) | ((code & 7u) << 20));
    return (u & 0x80u) ? -v : v;
}
__device__ __forceinline__ unsigned f2e4m3_sw(float f) {
    unsigned s = (__float_as_uint(f) >> 31) << 7;
    float a = fminf(fabsf(f), 448.0f);
    unsigned code;
    if (a >= 0.015625f) {
        unsigned x = __float_as_uint(a);
        x += 0x0007FFFFu + ((x >> 20) & 1u);
        code = (((x >> 23) - 120u) << 3) | ((x >> 20) & 7u);
    } else {
        code = (unsigned)__float2int_rn(a * 512.0f);
    }
    return s | code;
}
__device__ __forceinline__ float4 fp8x4f(unsigned v) {
#if FP8_HW
    using floatx2 = __attribute__((ext_vector_type(2))) float;
    floatx2 lo = __builtin_amdgcn_cvt_pk_f32_fp8((int)v, false);
    floatx2 hi = __builtin_amdgcn_cvt_pk_f32_fp8((int)v, true);
    return make_float4(lo[0], lo[1], hi[0], hi[1]);
#else
    return make_float4(e4m3f_sw(v & 255), e4m3f_sw((v >> 8) & 255),
                       e4m3f_sw((v >> 16) & 255), e4m3f_sw(v >> 24));
#endif
}
__device__ __forceinline__ unsigned f4fp8(float a, float b, float c, float d) {
#if FP8_HW
    int pk = 0;
    pk = __builtin_amdgcn_cvt_pk_fp8_f32(a, b, pk, false);
    pk = __builtin_amdgcn_cvt_pk_fp8_f32(c, d, pk, true);
    return (unsigned)pk;
#else
    return f2e4m3_sw(a) | (f2e4m3_sw(b) << 8) | (f2e4m3_sw(c) << 16) | (f2e4m3_sw(d) << 24);
#endif
}

#define NM_SCALE 3.0517578125e-5f  // 1/32768

#define GBODY(PAIR_AT)                                                              \
    {                                                                               \
        int k = 0;                                                                  \
        for (; k + 8 <= cn; k += 8) {                                               \
            unsigned pw[8];                                                         \
            _Pragma("unroll") for (int j = 0; j < 8; ++j) pw[j] = PAIR_AT(k + j);   \
            unsigned hvv[8];                                                        \
            _Pragma("unroll") for (int j = 0; j < 8; ++j)                           \
                hvv[j] = *(const unsigned*)(hb + (size_t)(pw[j] >> 15) * 32 + c4 * 4);\
            _Pragma("unroll") for (int j = 0; j < 8; ++j) {                         \
                float nm = (float)(pw[j] & 32767u) * NM_SCALE;                      \
                float4 f = fp8x4f(hvv[j]);                                          \
                acc.x = fmaf(nm, f.x, acc.x);                                       \
                acc.y = fmaf(nm, f.y, acc.y);                                       \
                acc.z = fmaf(nm, f.z, acc.z);                                       \
                acc.w = fmaf(nm, f.w, acc.w);                                       \
            }                                                                       \
        }                                                                           \
        for (; k + 4 <= cn; k += 4) {                                               \
            unsigned pw[4];                                                         \
            _Pragma("unroll") for (int j = 0; j < 4; ++j) pw[j] = PAIR_AT(k + j);   \
            unsigned hvv[4];                                                        \
            _Pragma("unroll") for (int j = 0; j < 4; ++j)                           \
                hvv[j] = *(const unsigned*)(hb + (size_t)(pw[j] >> 15) * 32 + c4 * 4);\
            _Pragma("unroll") for (int j = 0; j < 4; ++j) {                         \
                float nm = (float)(pw[j] & 32767u) * NM_SCALE;                      \
                float4 f = fp8x4f(hvv[j]);                                          \
                acc.x = fmaf(nm, f.x, acc.x);                                       \
                acc.y = fmaf(nm, f.y, acc.y);                                       \
                acc.z = fmaf(nm, f.z, acc.z);                                       \
                acc.w = fmaf(nm, f.w, acc.w);                                       \
            }                                                                       \
        }                                                                           \
        for (; k < cn; ++k) {                                                       \
            unsigned pw = PAIR_AT(k);                                               \
            unsigned hvv = *(const unsigned*)(hb + (size_t)(pw >> 15) * 32 + c4 * 4);\
            float nm = (float)(pw & 32767u) * NM_SCALE;                             \
            float4 f = fp8x4f(hvv);                                                 \
            acc.x = fmaf(nm, f.x, acc.x);                                           \
            acc.y = fmaf(nm, f.y, acc.y);                                           \
            acc.z = fmaf(nm, f.z, acc.z);                                           \
            acc.w = fmaf(nm, f.w, acc.w);                                           \
        }                                                                           \
    }

#define SPAIR_AT(i) spair[l0 + (i)]
#define GPAIR_AT(i) pp[(i)]

// ---------- gather phase (one GCN layer), grid-strided ----------
__device__ __forceinline__ void gather_phase(
    int MODE, char* smem, int tid,
    const unsigned char* __restrict__ hb, const int* __restrict__ off,
    const int* __restrict__ cntg, const float* __restrict__ dinv,
    const unsigned* __restrict__ pairs, const float* __restrict__ bias,
    const float* __restrict__ Wn, unsigned char* __restrict__ hout,
    unsigned short* __restrict__ h3out) {
    float* sW = (float*)smem;                       // 4096 B
    float* srow = (float*)(smem + 4096);            // 4224 B
    unsigned* spair = (unsigned*)(smem + 8320);     // 4096 B
    for (int lb = blockIdx.x; lb < GATHER_LOGICAL; lb += gridDim.x) {
        __syncthreads();
        if (MODE == 0) ((float4*)sW)[tid] = ((const float4*)Wn)[tid];
        int nb = lb * 32;
        int base = off[nb];
        int mb = off[nb + 32] - base;
        int mbc = min(mb, CAPL);
        for (int i = tid; i < mbc; i += 256) spair[i] = pairs[base + i];
        __syncthreads();
        int n = nb + (tid >> 3), c4 = tid & 7;
        int cn = cntg[n];
        int l0 = off[n] - base;
        const unsigned* pp = pairs + base + l0;
        float di = dinv[n];
        unsigned hu = *(const unsigned*)(hb + (size_t)n * 32 + c4 * 4);
        float4 acc = fp8x4f(hu);  // self term, coefficient 1
        if (l0 + cn <= CAPL) {
            GBODY(SPAIR_AT)
        } else {
            GBODY(GPAIR_AT)
        }
        int cb = c4 * 4;
        if (MODE == 0) {
            int ln = tid >> 3;
            srow[ln * 33 + cb + 0] = fmaxf(fmaf(di, acc.x, bias[cb + 0]), 0.0f);
            srow[ln * 33 + cb + 1] = fmaxf(fmaf(di, acc.y, bias[cb + 1]), 0.0f);
            srow[ln * 33 + cb + 2] = fmaxf(fmaf(di, acc.z, bias[cb + 2]), 0.0f);
            srow[ln * 33 + cb + 3] = fmaxf(fmaf(di, acc.w, bias[cb + 3]), 0.0f);
            __syncthreads();
            const float* rw = srow + ln * 33;
            float o0 = 0.f, o1 = 0.f, o2 = 0.f, o3 = 0.f;
#pragma unroll
            for (int kk = 0; kk < 32; ++kk) {
                float r = rw[kk];
                const float* wr = sW + kk * 32 + cb;
                o0 = fmaf(r, wr[0], o0);
                o1 = fmaf(r, wr[1], o1);
                o2 = fmaf(r, wr[2], o2);
                o3 = fmaf(r, wr[3], o3);
            }
            *(unsigned*)(hout + (size_t)n * 32 + cb) = f4fp8(di * o0, di * o1, di * o2, di * o3);
        } else {
            ushort4 ou;
            ou.x = f2bf(fmaxf(fmaf(di, acc.x, bias[cb + 0]), 0.0f));
            ou.y = f2bf(fmaxf(fmaf(di, acc.y, bias[cb + 1]), 0.0f));
            ou.z = f2bf(fmaxf(fmaf(di, acc.z, bias[cb + 2]), 0.0f));
            ou.w = f2bf(fmaxf(fmaf(di, acc.w, bias[cb + 3]), 0.0f));
            *((ushort4*)(h3out + (size_t)n * 32) + c4) = ou;
        }
    }
}

// ---------- the mega kernel: all phases, grid-synced ----------
__global__ __launch_bounds__(256) void k_mega(
    const int* __restrict__ eidx, const float* __restrict__ ew,
    const int* __restrict__ batch, const float* __restrict__ x,
    const float* __restrict__ W1, const float* __restrict__ b1,
    const float* __restrict__ W2, const float* __restrict__ b2,
    const float* __restrict__ W3, const float* __restrict__ b3,
    const float* __restrict__ Wout, const float* __restrict__ bout,
    char* __restrict__ ws, float* __restrict__ out) {
    const int* row = eidx;
    const int* col = eidx + NE;
    unsigned char* h1 = (unsigned char*)ws;
    unsigned char* h2 = h1 + (size_t)NN * HD;
    unsigned short* h3 = (unsigned short*)(h2 + (size_t)NN * HD);  // htmp during build
    unsigned* pairs = (unsigned*)(h3 + (size_t)NN * HD);
    uint2* staging = (uint2*)(pairs + NE);
    float* dinv = (float*)(staging + (size_t)P * SCAP);
    int* off = (int*)(dinv + NN);      // NN+1 (sentinel)
    int* cntg = off + NN + 1;
    int* pcnt = cntg + NN;
    float* gsum = (float*)(pcnt + P);
    float* gcnt = gsum + NG * HD;

    cg::grid_group grid = cg::this_grid();
    int tid = threadIdx.x;
    __shared__ __align__(16) char smem[12544];

    // ---- phase Z: zero pcnt | gsum | gcnt (contiguous) ----
    for (int i = blockIdx.x * 256 + tid; i < P + NG * HD + NG; i += gridDim.x * 256)
        pcnt[i] = 0;
    grid.sync();

    // ---- phase A: bin (196 logical) || gemm0 htmp = bf16(x@W1) (12500 logical) ----
    for (int lb = blockIdx.x; lb < NBIN + GEMM0_LOGICAL; lb += gridDim.x) {
        __syncthreads();
        if (lb < NBIN) {
            int* hist = (int*)smem;
            int* base_ = hist + P;
            int e0 = lb * CH;
            int nrem = min(CH, NE - e0);
            hist[tid] = 0;
            __syncthreads();
            for (int i = tid; i < nrem; i += 256)
                atomicAdd(&hist[(unsigned)col[e0 + i] / PART], 1);
            __syncthreads();
            int h = hist[tid];
            base_[tid] = h ? atomicAdd(&pcnt[tid], h) : 0;
            hist[tid] = 0;
            __syncthreads();
            for (int i = tid; i < nrem; i += 256) {
                int c = col[e0 + i];  // L2-hot re-read of own chunk
                int p = (unsigned)c / PART;
                int pos = base_[p] + atomicAdd(&hist[p], 1);
                uint2 v;
                v.x = (unsigned)(c - p * PART) | ((unsigned)row[e0 + i] << 9);
                v.y = __float_as_uint(ew[e0 + i]);
                staging[(size_t)p * SCAP + pos] = v;
            }
        } else {
            float* sW = (float*)smem;         // 4096 B
            float* sX = (float*)(smem + 4096);// 1024 B
            int base = (lb - NBIN) * 8;
            ((float4*)sW)[tid] = ((const float4*)W1)[tid];
            if (tid < 64) ((float4*)sX)[tid] = ((const float4*)(x + (size_t)base * 32))[tid];
            __syncthreads();
            int c = tid & 31, nl = tid >> 5;
            float acc = 0.0f;
#pragma unroll
            for (int k = 0; k < 32; ++k) acc = fmaf(sX[nl * 32 + k], sW[k * 32 + c], acc);
            h3[(size_t)(base + nl) * 32 + c] = f2bf(acc);
        }
    }
    grid.sync();

    // ---- phase B: CSR build + dinv + h1 = fp8(dinv*htmp) + pairs fill ----
    for (int p = blockIdx.x; p < P; p += gridDim.x) {
        __syncthreads();
        int* spc = (int*)smem;                  // 1024
        int* cnt_l = spc + P;                   // 1564
        float* wsum = (float*)(cnt_l + PART);   // 1564
        int* sc = (int*)(wsum + PART);          // 1564
        float* sdc = (float*)(sc + PART);       // 1564
        int* cur = (int*)(sdc + PART);          // 1564
        spc[tid] = pcnt[tid];
        __syncthreads();
#pragma unroll
        for (int d = 1; d < P; d <<= 1) {
            int t = (tid >= d) ? spc[tid - d] : 0;
            __syncthreads();
            spc[tid] += t;
            __syncthreads();
        }
        int m = pcnt[p];
        int pb = (p > 0) ? spc[p - 1] : 0;
        if (p == P - 1 && tid == 0) off[NN] = pb + m;  // sentinel
        for (int i = tid; i < PART; i += 256) { cnt_l[i] = 0; wsum[i] = 0.0f; }
        __syncthreads();
        const uint2* st = staging + (size_t)p * SCAP;
        for (int i = tid; i < m; i += 256) {
            uint2 v = st[i];
            int cl = v.x & 511;
            atomicAdd(&cnt_l[cl], 1);
            atomicAdd(&wsum[cl], __uint_as_float(v.y));
        }
        __syncthreads();
        for (int i = tid; i < PART; i += 256) sc[i] = cnt_l[i];
        __syncthreads();
        int i0 = tid, i1 = tid + 256;
#pragma unroll
        for (int d = 1; d < 512; d <<= 1) {
            int t0 = 0, t1 = 0;
            if (i0 >= d) t0 = sc[i0 - d];
            if (i1 < PART && i1 >= d) t1 = sc[i1 - d];
            __syncthreads();
            sc[i0] += t0;
            if (i1 < PART) sc[i1] += t1;
            __syncthreads();
        }
        for (int i = tid; i < PART; i += 256) {
            int excl = sc[i] - cnt_l[i];
            cur[i] = excl;
            float dv = rsqrtf(1.0f + wsum[i]);
            sdc[i] = dv;
            int n = p * PART + i;
            if (n < NN) {
                off[n] = pb + excl;
                cntg[n] = cnt_l[i];
                dinv[n] = dv;
            }
        }
        __syncthreads();
        for (int u = tid; u < PART * 8; u += 256) {
            int i = u >> 3, q = u & 7;
            int n = p * PART + i;
            if (n < NN) {
                ushort4 hv = *((const ushort4*)(h3 + (size_t)n * 32) + q);
                float dv = sdc[i];
                *(unsigned*)(h1 + (size_t)n * 32 + q * 4) =
                    f4fp8(dv * bf2f(hv.x), dv * bf2f(hv.y), dv * bf2f(hv.z), dv * bf2f(hv.w));
            }
        }
        unsigned* pr = pairs + pb;
        for (int ib = tid; ib < m; ib += 256 * 4) {
            uint2 v[4];
#pragma unroll
            for (int j = 0; j < 4; ++j) {
                int i = ib + j * 256;
                if (i < m) v[j] = st[i];
            }
#pragma unroll
            for (int j = 0; j < 4; ++j) {
                int i = ib + j * 256;
                if (i < m) {
                    int cl = v[j].x & 511;
                    int pos = atomicAdd(&cur[cl], 1);
                    unsigned q = (unsigned)__float2int_rn(__uint_as_float(v[j].y) * 32768.0f);
                    q = min(q, 32767u);
                    pr[pos] = ((v[j].x >> 9) << 15) | q;
                }
            }
        }
    }
    grid.sync();

    // ---- phases C/D/E: three GCN layers ----
    gather_phase(0, smem, tid, h1, off, cntg, dinv, pairs, b1, W2, h2, nullptr);
    grid.sync();
    gather_phase(0, smem, tid, h2, off, cntg, dinv, pairs, b2, W3, h1, nullptr);
    grid.sync();
    gather_phase(1, smem, tid, h1, off, cntg, dinv, pairs, b3, nullptr, nullptr, h3);
    grid.sync();

    // ---- phase F: pool (NG graphs x 16 slices) ----
    for (int lb = blockIdx.x; lb < POOL_LOGICAL; lb += gridDim.x) {
        __syncthreads();
        int g = lb >> 4, s = lb & 15;
        int* sb = (int*)smem;
        float* red = (float*)(smem + 16);
        if (tid == 0) {
            int lo = 0, hi = NN;
            while (lo < hi) { int mm = (lo + hi) >> 1; if (batch[mm] < g) lo = mm + 1; else hi = mm; }
            sb[0] = lo;
            lo = 0; hi = NN;
            while (lo < hi) { int mm = (lo + hi) >> 1; if (batch[mm] < g + 1) lo = mm + 1; else hi = mm; }
            sb[1] = lo;
        }
        __syncthreads();
        int start = sb[0], len = sb[1] - sb[0];
        int a = start + (int)((long long)len * s / 16);
        int b = start + (int)((long long)len * (s + 1) / 16);
        int c = tid & 31, grp = tid >> 5;
        float acc = 0.0f;
        for (int n = a + grp; n < b; n += 8)
            acc += bf2f(h3[(size_t)n * 32 + c]);
        red[grp * 32 + c] = acc;
        __syncthreads();
        if (tid < 32) {
            float sum = 0.0f;
#pragma unroll
            for (int gr = 0; gr < 8; ++gr) sum += red[gr * 32 + tid];
            if (sum != 0.0f) atomicAdd(&gsum[g * HD + tid], sum);
        }
        if (tid == 0 && b > a) atomicAdd(&gcnt[g], (float)(b - a));
    }
    grid.sync();

    // ---- phase G: head (block 0) ----
    if (blockIdx.x == 0) {
        float* pooled = (float*)smem;             // NG*33 floats = 8448 B
        float* sWh = (float*)(smem + 8448);       // 256 floats
        float* slog = (float*)(smem + 9472);      // NG*NC floats
        sWh[tid] = Wout[tid];
        for (int i = tid; i < NG * HD; i += 256) {
            int g = i >> 5, c = i & 31;
            pooled[g * 33 + c] = gsum[i] / fmaxf(gcnt[g], 1.0f);
        }
        __syncthreads();
        for (int i = tid; i < NG * NC; i += 256) {
            int g = i >> 3, c = i & 7;
            float l = bout[c];
            const float* pr2 = pooled + g * 33;
#pragma unroll
            for (int k = 0; k < 32; ++k) l = fmaf(pr2[k], sWh[k * NC + c], l);
            slog[i] = l;
        }
        __syncthreads();
        if (tid < NG) {
            const float* sl = slog + tid * NC;
            float mx = sl[0];
#pragma unroll
            for (int i = 1; i < NC; ++i) mx = fmaxf(mx, sl[i]);
            float s = 0.0f;
#pragma unroll
            for (int i = 0; i < NC; ++i) s += expf(sl[i] - mx);
            float lse = mx + logf(s);
#pragma unroll
            for (int i = 0; i < NC; ++i) out[tid * NC + i] = sl[i] - lse;
        }
    }
}

extern "C" void kernel_launch(void* const* d_in, const int* in_sizes, int n_in,
                              void* d_out, int out_size, void* d_ws, size_t ws_size,
                              hipStream_t stream) {
    const float* x     = (const float*)d_in[0];
    const int*   eidx  = (const int*)d_in[1];
    const float* ew    = (const float*)d_in[2];
    const int*   batch = (const int*)d_in[3];
    const float* W1 = (const float*)d_in[4];
    const float* b1 = (const float*)d_in[5];
    const float* W2 = (const float*)d_in[6];
    const float* b2 = (const float*)d_in[7];
    const float* W3 = (const float*)d_in[8];
    const float* b3 = (const float*)d_in[9];
    const float* Wout = (const float*)d_in[10];
    const float* bout = (const float*)d_in[11];
    char* ws = (char*)d_ws;
    float* outp = (float*)d_out;

    int maxB = 0;
    hipOccupancyMaxActiveBlocksPerMultiprocessor(&maxB, (const void*)k_mega, 256, 0);
    if (maxB < 1) maxB = 1;
    int nbl = maxB * 256;  // 256 CUs on MI355X
    if (nbl > 2048) nbl = 2048;
    if (nbl < 256) nbl = 256;

    void* args[] = { (void*)&eidx, (void*)&ew, (void*)&batch, (void*)&x,
                     (void*)&W1, (void*)&b1, (void*)&W2, (void*)&b2,
                     (void*)&W3, (void*)&b3, (void*)&Wout, (void*)&bout,
                     (void*)&ws, (void*)&outp };
    hipLaunchCooperativeKernel((const void*)k_mega, dim3(nbl), dim3(256), args, 0, stream);
}

// Round 19
// 124.263 us; speedup vs baseline: 6.3702x; 6.3702x over previous
//
#include <hip/hip_runtime.h>
#include <math.h>

#define NN 100000
#define NE 1600000
#define HD 32
#define NG 64
#define NC 8

#define P 256        // partitions
#define PART 391     // nodes per partition; 391*256 = 100096 >= NN
#define SCAP 7000    // staging capacity per partition (Poisson(6250), +9 sigma)
#define CH 8192      // edges per k_bin block
#define NBIN ((NE + CH - 1) / CH)     // 196
#define GEMM0_BLOCKS32 (NN / 32)      // 3125 (32 nodes/block @1024 thr)
#define NORM_BLOCKS (NN * 8 / 256)    // 3125 (gather grid, 32 nodes/block)
#define CAPL 1024                     // LDS pairs-slice capacity (mean 512, sigma 23)

__device__ __forceinline__ float bf2f(unsigned short u) {
    return __uint_as_float(((unsigned int)u) << 16);
}
__device__ __forceinline__ unsigned short f2bf(float f) {
    unsigned int b = __float_as_uint(f);
    b = (b + 0x7FFFu + ((b >> 16) & 1u)) >> 16;  // RNE
    return (unsigned short)b;
}

// ---- fp8 helpers: hardware cvt if available, manual e4m3 fallback ----
#if __has_builtin(__builtin_amdgcn_cvt_pk_f32_fp8) && __has_builtin(__builtin_amdgcn_cvt_pk_fp8_f32)
#define FP8_HW 1
#else
#define FP8_HW 0
#endif

__device__ __forceinline__ float e4m3f_sw(unsigned u) {
    unsigned code = u & 0x7fu;
    unsigned e = code >> 3;
    float v;
    if (e == 0) v = (float)code * 0.001953125f;
    else v = __uint_as_float(((e + 120u) << 23) | ((code & 7u) << 20));
    return (u & 0x80u) ? -v : v;
}
__device__ __forceinline__ unsigned f2e4m3_sw(float f) {
    unsigned s = (__float_as_uint(f) >> 31) << 7;
    float a = fminf(fabsf(f), 448.0f);
    unsigned code;
    if (a >= 0.015625f) {
        unsigned x = __float_as_uint(a);
        x += 0x0007FFFFu + ((x >> 20) & 1u);
        code = (((x >> 23) - 120u) << 3) | ((x >> 20) & 7u);
    } else {
        code = (unsigned)__float2int_rn(a * 512.0f);
    }
    return s | code;
}

__device__ __forceinline__ float4 fp8x4f(unsigned v) {
#if FP8_HW
    using floatx2 = __attribute__((ext_vector_type(2))) float;
    floatx2 lo = __builtin_amdgcn_cvt_pk_f32_fp8((int)v, false);
    floatx2 hi = __builtin_amdgcn_cvt_pk_f32_fp8((int)v, true);
    return make_float4(lo[0], lo[1], hi[0], hi[1]);
#else
    return make_float4(e4m3f_sw(v & 255), e4m3f_sw((v >> 8) & 255),
                       e4m3f_sw((v >> 16) & 255), e4m3f_sw(v >> 24));
#endif
}
__device__ __forceinline__ unsigned f4fp8(float a, float b, float c, float d) {
#if FP8_HW
    int pk = 0;
    pk = __builtin_amdgcn_cvt_pk_fp8_f32(a, b, pk, false);
    pk = __builtin_amdgcn_cvt_pk_fp8_f32(c, d, pk, true);
    return (unsigned)pk;
#else
    return f2e4m3_sw(a) | (f2e4m3_sw(b) << 8) | (f2e4m3_sw(c) << 16) | (f2e4m3_sw(d) << 24);
#endif
}

// ---------- phase 1: bin edges (196 blocks) || gemm0: htmp = bf16(x@W1) (3125 blocks) ----------
__global__ __launch_bounds__(1024) void k_bin_gemm0(const int* __restrict__ row,
                                                    const int* __restrict__ col,
                                                    const float* __restrict__ w,
                                                    int* __restrict__ pcnt,
                                                    uint2* __restrict__ staging,
                                                    const float* __restrict__ x,
                                                    const float* __restrict__ W1,
                                                    unsigned short* __restrict__ htmp) {
    int tid = threadIdx.x;
    if (blockIdx.x < NBIN) {
        __shared__ int scol[CH];   // 32 KB (1024-thr blocks are thread-capped at 2/CU anyway)
        __shared__ int hist[P];
        __shared__ int base_[P];
        int e0 = blockIdx.x * CH;
        int nrem = min(CH, NE - e0);
        if (tid < P) hist[tid] = 0;
        __syncthreads();
        for (int i = tid; i < nrem; i += 1024) {
            int c = col[e0 + i];
            scol[i] = c;
            atomicAdd(&hist[(unsigned)c / PART], 1);
        }
        __syncthreads();
        if (tid < P) {
            int h = hist[tid];
            base_[tid] = h ? atomicAdd(&pcnt[tid], h) : 0;
            hist[tid] = 0;
        }
        __syncthreads();
        for (int i = tid; i < nrem; i += 1024) {
            int c = scol[i];
            int p = (unsigned)c / PART;
            int pos = base_[p] + atomicAdd(&hist[p], 1);
            uint2 v;
            v.x = (unsigned)(c - p * PART) | ((unsigned)row[e0 + i] << 9);
            v.y = __float_as_uint(w[e0 + i]);
            staging[(size_t)p * SCAP + pos] = v;
        }
    } else {
        __shared__ float sW[32 * 32];
        __shared__ float sX[32 * 32];
        int base = (blockIdx.x - NBIN) * 32;
        if (tid < 256) {
            ((float4*)sW)[tid] = ((const float4*)W1)[tid];
            ((float4*)sX)[tid] = ((const float4*)(x + (size_t)base * 32))[tid];
        }
        __syncthreads();
        int nl = tid >> 5, c = tid & 31;
        float acc = 0.0f;
#pragma unroll
        for (int k = 0; k < 32; ++k) acc = fmaf(sX[nl * 32 + k], sW[k * 32 + c], acc);
        htmp[(size_t)(base + nl) * 32 + c] = f2bf(acc);
    }
}

// ---------- phase 2: fused CSR build: counts+wsum -> scan -> dinv
//            -> h1 = fp8(dinv*htmp) -> pairs = (row<<15 | q15(w)) ----------
__global__ __launch_bounds__(512) void k_csr(const int* __restrict__ pcnt,
                                             const uint2* __restrict__ staging,
                                             int* __restrict__ off,
                                             float* __restrict__ dinv,
                                             const unsigned short* __restrict__ htmp,
                                             unsigned char* __restrict__ h1,
                                             unsigned* __restrict__ pairs) {
    __shared__ int spc[P];
    __shared__ int cnt_l[PART];
    __shared__ float wsum[PART];
    __shared__ int sc[PART];
    __shared__ float sdc[PART];
    __shared__ int cur[PART];
    int p = blockIdx.x, tid = threadIdx.x;
    if (tid < P) spc[tid] = pcnt[tid];
    __syncthreads();
#pragma unroll
    for (int d = 1; d < P; d <<= 1) {
        int t = 0;
        if (tid < P && tid >= d) t = spc[tid - d];
        __syncthreads();
        if (tid < P) spc[tid] += t;
        __syncthreads();
    }
    int m = pcnt[p];
    int pb = (p > 0) ? spc[p - 1] : 0;
    if (p == P - 1 && tid == 0) off[NN] = pb + m;  // sentinel (upper buckets empty)
    for (int i = tid; i < PART; i += 512) { cnt_l[i] = 0; wsum[i] = 0.0f; }
    __syncthreads();
    const uint2* st = staging + (size_t)p * SCAP;
    for (int i = tid; i < m; i += 512) {
        uint2 v = st[i];
        int cl = v.x & 511;
        atomicAdd(&cnt_l[cl], 1);
        atomicAdd(&wsum[cl], __uint_as_float(v.y));
    }
    __syncthreads();
    for (int i = tid; i < PART; i += 512) sc[i] = cnt_l[i];
    __syncthreads();
#pragma unroll
    for (int d = 1; d < 512; d <<= 1) {
        int t = 0;
        if (tid < PART && tid >= d) t = sc[tid - d];
        __syncthreads();
        if (tid < PART) sc[tid] += t;
        __syncthreads();
    }
    for (int i = tid; i < PART; i += 512) {
        int excl = sc[i] - cnt_l[i];
        cur[i] = excl;
        float dv = rsqrtf(1.0f + wsum[i]);
        sdc[i] = dv;
        int n = p * PART + i;
        if (n < NN) {
            off[n] = pb + excl;
            dinv[n] = dv;
        }
    }
    __syncthreads();
    // rescale h1' = fp8(dinv * htmp)  (partition-local, coalesced)
    for (int u = tid; u < PART * 8; u += 512) {
        int i = u >> 3, q = u & 7;
        int n = p * PART + i;
        if (n < NN) {
            ushort4 hv = *((const ushort4*)(htmp + (size_t)n * 32) + q);
            float dv = sdc[i];
            *(unsigned*)(h1 + (size_t)n * 32 + q * 4) =
                f4fp8(dv * bf2f(hv.x), dv * bf2f(hv.y), dv * bf2f(hv.z), dv * bf2f(hv.w));
        }
    }
    // fill pairs (staging slab is L2-warm from the count pass)
    unsigned* pr = pairs + pb;
    for (int ib = tid; ib < m; ib += 512 * 4) {
        uint2 v[4];
#pragma unroll
        for (int j = 0; j < 4; ++j) {
            int i = ib + j * 512;
            if (i < m) v[j] = st[i];
        }
#pragma unroll
        for (int j = 0; j < 4; ++j) {
            int i = ib + j * 512;
            if (i < m) {
                int cl = v[j].x & 511;
                int pos = atomicAdd(&cur[cl], 1);
                unsigned q = (unsigned)__float2int_rn(__uint_as_float(v[j].y) * 32768.0f);
                q = min(q, 32767u);
                pr[pos] = ((v[j].x >> 9) << 15) | q;
            }
        }
    }
}

// ---------- gather on h' (fp8), block pairs-slice staged in LDS ----------
// agg = di*(h'[n] + sum w*h'[r])
// MODE 0: hout = fp8( di * (relu(agg + bias) @ Wn) )   MODE 1: h3 = bf16(relu(agg + b3))
#define NM_SCALE 3.0517578125e-5f  // 1/32768

#define GBODY(PAIR_AT)                                                              \
    {                                                                               \
        int k = 0;                                                                  \
        for (; k + 8 <= cn; k += 8) {                                               \
            unsigned pw[8];                                                         \
            _Pragma("unroll") for (int j = 0; j < 8; ++j) pw[j] = PAIR_AT(k + j);   \
            unsigned hv[8];                                                         \
            _Pragma("unroll") for (int j = 0; j < 8; ++j)                           \
                hv[j] = *(const unsigned*)(hb + (size_t)(pw[j] >> 15) * 32 + c4 * 4);\
            _Pragma("unroll") for (int j = 0; j < 8; ++j) {                         \
                float nm = (float)(pw[j] & 32767u) * NM_SCALE;                      \
                float4 f = fp8x4f(hv[j]);                                           \
                acc.x = fmaf(nm, f.x, acc.x);                                       \
                acc.y = fmaf(nm, f.y, acc.y);                                       \
                acc.z = fmaf(nm, f.z, acc.z);                                       \
                acc.w = fmaf(nm, f.w, acc.w);                                       \
            }                                                                       \
        }                                                                           \
        for (; k + 4 <= cn; k += 4) {                                               \
            unsigned pw[4];                                                         \
            _Pragma("unroll") for (int j = 0; j < 4; ++j) pw[j] = PAIR_AT(k + j);   \
            unsigned hv[4];                                                         \
            _Pragma("unroll") for (int j = 0; j < 4; ++j)                           \
                hv[j] = *(const unsigned*)(hb + (size_t)(pw[j] >> 15) * 32 + c4 * 4);\
            _Pragma("unroll") for (int j = 0; j < 4; ++j) {                         \
                float nm = (float)(pw[j] & 32767u) * NM_SCALE;                      \
                float4 f = fp8x4f(hv[j]);                                           \
                acc.x = fmaf(nm, f.x, acc.x);                                       \
                acc.y = fmaf(nm, f.y, acc.y);                                       \
                acc.z = fmaf(nm, f.z, acc.z);                                       \
                acc.w = fmaf(nm, f.w, acc.w);                                       \
            }                                                                       \
        }                                                                           \
        for (; k < cn; ++k) {                                                       \
            unsigned pw = PAIR_AT(k);                                               \
            unsigned hv = *(const unsigned*)(hb + (size_t)(pw >> 15) * 32 + c4 * 4);\
            float nm = (float)(pw & 32767u) * NM_SCALE;                             \
            float4 f = fp8x4f(hv);                                                  \
            acc.x = fmaf(nm, f.x, acc.x);                                           \
            acc.y = fmaf(nm, f.y, acc.y);                                           \
            acc.z = fmaf(nm, f.z, acc.z);                                           \
            acc.w = fmaf(nm, f.w, acc.w);                                           \
        }                                                                           \
    }

#define SPAIR_AT(i) spair[l0 + (i)]
#define GPAIR_AT(i) pp[(i)]

template <int MODE>
__global__ __launch_bounds__(256) void k_gather(const unsigned char* __restrict__ hb,
                                                const int* __restrict__ off,
                                                const float* __restrict__ dinv,
                                                const unsigned* __restrict__ pairs,
                                                const float* __restrict__ bias,
                                                const float* __restrict__ Wn,
                                                unsigned char* __restrict__ hout,
                                                unsigned short* __restrict__ h3out) {
    __shared__ float sW[32 * 32];
    __shared__ float srow[32 * 33];
    __shared__ unsigned spair[CAPL];
    int tid = threadIdx.x;
    if (MODE == 0) ((float4*)sW)[tid] = ((const float4*)Wn)[tid];
    int nb = blockIdx.x * 32;      // first node of this block
    int base = off[nb];
    int mb = off[nb + 32] - base;  // block's contiguous pairs-slice length
    int mbc = min(mb, CAPL);
    for (int i = tid; i < mbc; i += 256) spair[i] = pairs[base + i];
    __syncthreads();
    int t = blockIdx.x * 256 + tid;  // NN*8 exact
    int n = t >> 3, c4 = t & 7;
    int offn = off[n];
    int cn = off[n + 1] - offn;
    int l0 = offn - base;
    const unsigned* pp = pairs + offn;
    float di = dinv[n];
    unsigned hu = *(const unsigned*)(hb + (size_t)n * 32 + c4 * 4);
    float4 acc = fp8x4f(hu);  // self term, coefficient 1
    if (l0 + cn <= CAPL) {
        GBODY(SPAIR_AT)
    } else {
        GBODY(GPAIR_AT)
    }
    int cb = c4 * 4;
    if (MODE == 0) {
        int ln = tid >> 3;
        srow[ln * 33 + cb + 0] = fmaxf(fmaf(di, acc.x, bias[cb + 0]), 0.0f);
        srow[ln * 33 + cb + 1] = fmaxf(fmaf(di, acc.y, bias[cb + 1]), 0.0f);
        srow[ln * 33 + cb + 2] = fmaxf(fmaf(di, acc.z, bias[cb + 2]), 0.0f);
        srow[ln * 33 + cb + 3] = fmaxf(fmaf(di, acc.w, bias[cb + 3]), 0.0f);
        __syncthreads();
        const float* rw = srow + ln * 33;
        float o0 = 0.f, o1 = 0.f, o2 = 0.f, o3 = 0.f;
#pragma unroll
        for (int kk = 0; kk < 32; ++kk) {
            float r = rw[kk];
            const float* wr = sW + kk * 32 + cb;
            o0 = fmaf(r, wr[0], o0);
            o1 = fmaf(r, wr[1], o1);
            o2 = fmaf(r, wr[2], o2);
            o3 = fmaf(r, wr[3], o3);
        }
        *(unsigned*)(hout + (size_t)n * 32 + cb) = f4fp8(di * o0, di * o1, di * o2, di * o3);
    } else {
        ushort4 ou;
        ou.x = f2bf(fmaxf(fmaf(di, acc.x, bias[cb + 0]), 0.0f));
        ou.y = f2bf(fmaxf(fmaf(di, acc.y, bias[cb + 1]), 0.0f));
        ou.z = f2bf(fmaxf(fmaf(di, acc.z, bias[cb + 2]), 0.0f));
        ou.w = f2bf(fmaxf(fmaf(di, acc.w, bias[cb + 3]), 0.0f));
        *((ushort4*)(h3out + (size_t)n * 32) + c4) = ou;
    }
}

// ---------- pool: 512 blocks (8 slices per graph) -> gsum/gcnt atomics ----------
__global__ __launch_bounds__(1024) void k_pool(const unsigned short* __restrict__ h3,
                                               const int* __restrict__ batch,
                                               float* __restrict__ gsum,
                                               float* __restrict__ gcnt) {
    int g = blockIdx.x >> 3, s = blockIdx.x & 7;
    __shared__ int sb[2];
    if (threadIdx.x == 0) {
        int lo = 0, hi = NN;
        while (lo < hi) { int m = (lo + hi) >> 1; if (batch[m] < g) lo = m + 1; else hi = m; }
        sb[0] = lo;
        lo = 0; hi = NN;
        while (lo < hi) { int m = (lo + hi) >> 1; if (batch[m] < g + 1) lo = m + 1; else hi = m; }
        sb[1] = lo;
    }
    __syncthreads();
    int start = sb[0], len = sb[1] - sb[0];
    int a = start + (int)((long long)len * s / 8);
    int b = start + (int)((long long)len * (s + 1) / 8);
    int c = threadIdx.x & 31, grp = threadIdx.x >> 5;
    float acc = 0.0f;
    for (int n = a + grp; n < b; n += 32)
        acc += bf2f(h3[(size_t)n * 32 + c]);
    __shared__ float red[32 * 32];
    red[grp * 32 + c] = acc;
    __syncthreads();
    if (threadIdx.x < 32) {
        float sum = 0.0f;
#pragma unroll
        for (int gr = 0; gr < 32; ++gr) sum += red[gr * 32 + threadIdx.x];
        if (sum != 0.0f) atomicAdd(&gsum[g * HD + threadIdx.x], sum);
    }
    if (threadIdx.x == 0 && b > a) atomicAdd(&gcnt[g], (float)(b - a));
}

// ---------- head: pooled = gsum/gcnt; logits = pooled@Wout+bout; log_softmax ----------
__global__ __launch_bounds__(256) void k_head(const float* __restrict__ gsum,
                                              const float* __restrict__ gcnt,
                                              const float* __restrict__ Wout,
                                              const float* __restrict__ bout,
                                              float* __restrict__ out) {
    __shared__ float pooled[NG * 33];
    __shared__ float sW[32 * NC];
    __shared__ float slog[NG * NC];
    int tid = threadIdx.x;
    sW[tid] = Wout[tid];  // 256 = 32*8
    for (int i = tid; i < NG * HD; i += 256) {
        int g = i >> 5, c = i & 31;
        pooled[g * 33 + c] = gsum[i] / fmaxf(gcnt[g], 1.0f);
    }
    __syncthreads();
    for (int i = tid; i < NG * NC; i += 256) {
        int g = i >> 3, c = i & 7;
        float l = bout[c];
        const float* pr = pooled + g * 33;
#pragma unroll
        for (int k = 0; k < 32; ++k) l = fmaf(pr[k], sW[k * NC + c], l);
        slog[i] = l;
    }
    __syncthreads();
    if (tid < NG) {
        const float* sl = slog + tid * NC;
        float m = sl[0];
#pragma unroll
        for (int i = 1; i < NC; ++i) m = fmaxf(m, sl[i]);
        float s = 0.0f;
#pragma unroll
        for (int i = 0; i < NC; ++i) s += expf(sl[i] - m);
        float lse = m + logf(s);
#pragma unroll
        for (int i = 0; i < NC; ++i) out[tid * NC + i] = sl[i] - lse;
    }
}

extern "C" void kernel_launch(void* const* d_in, const int* in_sizes, int n_in,
                              void* d_out, int out_size, void* d_ws, size_t ws_size,
                              hipStream_t stream) {
    const float* x     = (const float*)d_in[0];
    const int*   eidx  = (const int*)d_in[1];
    const float* ew    = (const float*)d_in[2];
    const int*   batch = (const int*)d_in[3];
    const float* W1 = (const float*)d_in[4];
    const float* b1 = (const float*)d_in[5];
    const float* W2 = (const float*)d_in[6];
    const float* b2 = (const float*)d_in[7];
    const float* W3 = (const float*)d_in[8];
    const float* b3 = (const float*)d_in[9];
    const float* Wout = (const float*)d_in[10];
    const float* bout = (const float*)d_in[11];
    float* out = (float*)d_out;

    const int* row = eidx;        // sources
    const int* col = eidx + NE;   // targets

    // layout: h1 fp8 | h2 fp8 | h3/htmp bf16 | pairs(4B) | staging | dinv | off(NN+1)
    //         | [pcnt | gsum | gcnt] (zeroed)
    unsigned char* h1 = (unsigned char*)d_ws;                    // 3.2 MB
    unsigned char* h2 = h1 + (size_t)NN * HD;                    // 3.2 MB
    unsigned short* h3 = (unsigned short*)(h2 + (size_t)NN * HD);// 6.4 MB (htmp during build)
    unsigned* pairs = (unsigned*)(h3 + (size_t)NN * HD);         // 6.4 MB
    uint2* staging = (uint2*)(pairs + NE);                       // 14.3 MB
    float* dinv = (float*)(staging + (size_t)P * SCAP);          // 0.4 MB
    int* off  = (int*)(dinv + NN);                               // NN+1 ints
    int* pcnt = off + NN + 1;                                    // P ints
    float* gsum = (float*)(pcnt + P);                            // NG*HD
    float* gcnt = gsum + NG * HD;                                // NG

    hipMemsetAsync(pcnt, 0, (P + NG * HD + NG) * sizeof(int), stream);
    k_bin_gemm0<<<NBIN + GEMM0_BLOCKS32, 1024, 0, stream>>>(row, col, ew, pcnt, staging,
                                                            x, W1, h3 /*htmp*/);
    k_csr<<<P, 512, 0, stream>>>(pcnt, staging, off, dinv, h3 /*htmp*/, h1, pairs);
    k_gather<0><<<NORM_BLOCKS, 256, 0, stream>>>(h1, off, dinv, pairs, b1, W2,
                                                 h2, nullptr);
    k_gather<0><<<NORM_BLOCKS, 256, 0, stream>>>(h2, off, dinv, pairs, b2, W3,
                                                 h1, nullptr);
    k_gather<1><<<NORM_BLOCKS, 256, 0, stream>>>(h1, off, dinv, pairs, b3, nullptr,
                                                 nullptr, h3);
    k_pool<<<NG * 8, 1024, 0, stream>>>(h3, batch, gsum, gcnt);
    k_head<<<1, 256, 0, stream>>>(gsum, gcnt, Wout, bout, out);
}